// Round 24
// baseline (128.672 us; speedup 1.0000x reference)
//
#include <hip/hip_runtime.h>
#include <stdint.h>

#define CB 32
#define CT 512
#define CK 256
#define SHIFT 5.0f
#define NUMOFF (64 + 14 * CB * CK)   // numerator partials: [8][CB]

typedef _Float16 f16x8 __attribute__((ext_vector_type(8)));
typedef float f32x4 __attribute__((ext_vector_type(4)));

__device__ inline uint32_t pk2(float a, float b) {
    return __builtin_bit_cast(uint32_t,
        __builtin_amdgcn_cvt_pkrtz(__expf(a), __expf(b)));
}

// Barrier draining LDS only; global prefetches stay in flight.
__device__ inline void lds_barrier() {
    asm volatile("s_waitcnt lgkmcnt(0)\n\ts_barrier" ::: "memory");
}

template <int CTRL>
__device__ inline float dpp_maxf(float x) {
    int yi = __builtin_amdgcn_update_dpp(
        __builtin_bit_cast(int, x), __builtin_bit_cast(int, x),
        CTRL, 0xF, 0xF, false);
    return fmaxf(x, __builtin_bit_cast(float, yi));
}

__device__ inline float wave_max(float x) {
    x = dpp_maxf<0x111>(x);
    x = dpp_maxf<0x112>(x);
    x = dpp_maxf<0x114>(x);
    x = dpp_maxf<0x118>(x);
    x = dpp_maxf<0x142>(x);
    x = dpp_maxf<0x143>(x);
    return __builtin_bit_cast(float,
        __builtin_amdgcn_readlane(__builtin_bit_cast(int, x), 63));
}

// FWD B-frag: B[k][col] = exp(trans[k][col]) (strided rows).
#define MKB_F(kt, n) f16x8 B_##kt##_##n; {                                   \
    const float* tp = trans + (size_t)((kt) * 32 + ko8) * CK + (colg + (n) * 16); \
    uint4 u_;                                                                \
    u_.x = pk2(tp[0],      tp[CK]);                                          \
    u_.y = pk2(tp[2 * CK], tp[3 * CK]);                                      \
    u_.z = pk2(tp[4 * CK], tp[5 * CK]);                                      \
    u_.w = pk2(tp[6 * CK], tp[7 * CK]);                                      \
    B_##kt##_##n = __builtin_bit_cast(f16x8, u_); }

// BWD B-frag: B[k][col] = exp(trans[col][k]) (contiguous k).
#define MKB_B(kt, n) f16x8 B_##kt##_##n; {                                   \
    const float* tp = trans + (size_t)(colg + (n) * 16) * CK + ((kt) * 32 + ko8); \
    uint4 u_;                                                                \
    u_.x = pk2(tp[0], tp[1]);                                                \
    u_.y = pk2(tp[2], tp[3]);                                                \
    u_.z = pk2(tp[4], tp[5]);                                                \
    u_.w = pk2(tp[6], tp[7]);                                                \
    B_##kt##_##n = __builtin_bit_cast(f16x8, u_); }

#define LOADB(MK) MK(0,0) MK(0,1) MK(1,0) MK(1,1) MK(2,0) MK(2,1) MK(3,0) MK(3,1) \
                  MK(4,0) MK(4,1) MK(5,0) MK(5,1) MK(6,0) MK(6,1) MK(7,0) MK(7,1)

#define MM(kt)                                                               \
    accA = __builtin_amdgcn_mfma_f32_16x16x32_f16(a##kt##_, B_##kt##_0, accA, 0, 0, 0); \
    accB = __builtin_amdgcn_mfma_f32_16x16x32_f16(a##kt##_, B_##kt##_1, accB, 0, 0, 0);

#define MFMA_STEP(pb)                                                        \
    f16x8 a0_ = *reinterpret_cast<const f16x8*>((pb) + 0   + ko8);           \
    f16x8 a1_ = *reinterpret_cast<const f16x8*>((pb) + 32  + ko8);           \
    f16x8 a2_ = *reinterpret_cast<const f16x8*>((pb) + 64  + ko8);           \
    f16x8 a3_ = *reinterpret_cast<const f16x8*>((pb) + 96  + ko8);           \
    f16x8 a4_ = *reinterpret_cast<const f16x8*>((pb) + 128 + ko8);           \
    f16x8 a5_ = *reinterpret_cast<const f16x8*>((pb) + 160 + ko8);           \
    f16x8 a6_ = *reinterpret_cast<const f16x8*>((pb) + 192 + ko8);           \
    f16x8 a7_ = *reinterpret_cast<const f16x8*>((pb) + 224 + ko8);           \
    f32x4 accA = {0.f, 0.f, 0.f, 0.f};                                       \
    f32x4 accB = {0.f, 0.f, 0.f, 0.f};                                       \
    MM(0) MM(1) MM(2) MM(3) MM(4) MM(5) MM(6) MM(7)

// Full fwd run over t in [T_LO, T_HI], alpha init AJ_INIT, result -> OUTP.
// Barriers: 2 (prologue) + (T_HI - T_LO + 1) (steps).
#define FWD_RUN(T_LO, T_HI, AJ_INIT, OUTP) {                                 \
    LOADB(MKB_F)                                                             \
    float aj = (AJ_INIT);                                                    \
    float emit_next = emB[(size_t)(T_LO) * CK + sj];                         \
    {   const float mw = wave_max(aj);                                       \
        if (l == 0) wmaxlS[0][w] = mw; }                                     \
    __syncthreads();                                                         \
    float Mref;                                                              \
    {   const float4 wa = *reinterpret_cast<const float4*>(&wmaxlS[0][0]);   \
        const float4 wb = *reinterpret_cast<const float4*>(&wmaxlS[0][4]);   \
        Mref = fmaxf(fmaxf(fmaxf(wa.x, wa.y), fmaxf(wa.z, wa.w)),            \
                     fmaxf(fmaxf(wb.x, wb.y), fmaxf(wb.z, wb.w))) + SHIFT; } \
    __syncthreads();                                                         \
    for (int t = (T_LO); t <= (T_HI); ++t) {                                 \
        const float emit_t = emit_next;                                      \
        const int nxt = (t + 1 <= (T_HI)) ? (t + 1) : (T_HI);                \
        emit_next = emB[(size_t)nxt * CK + sj];                              \
        const int bsel = t & 1;                                              \
        const float mw = wave_max(aj);                                       \
        if (l == 0) wmaxlS[bsel][w] = mw;                                    \
        const float pv = __expf(aj - Mref);                                  \
        if (l < 32) pbufS[bsel][w * 32 + l] = (_Float16)pv;                  \
        lds_barrier();                                                       \
        const float4 wa = *reinterpret_cast<const float4*>(&wmaxlS[bsel][0]);\
        const float4 wb = *reinterpret_cast<const float4*>(&wmaxlS[bsel][4]);\
        const float Mnext = fmaxf(fmaxf(fmaxf(wa.x, wa.y), fmaxf(wa.z, wa.w)), \
                                  fmaxf(fmaxf(wb.x, wb.y), fmaxf(wb.z, wb.w))) + SHIFT; \
        MFMA_STEP(pbufS[bsel])                                               \
        const float s = nsel ? accB[0] : accA[0];                            \
        const float anew = Mref + __logf(s) + emit_t;                        \
        aj = (mask_lds[t] != 0.f) ? anew : aj;                               \
        Mref = Mnext;                                                        \
    }                                                                        \
    if (l < 32) (OUTP)[w * 32 + l] = aj; }

// Full bwd run over tn in [TN_HI down to TN_LO], 0-init, result -> OUTP.
// Barriers: 3 (prologue) + (TN_HI - TN_LO + 1) (steps).
#define BWD_RUN(TN_LO, TN_HI, OUTP) {                                        \
    LOADB(MKB_B)                                                             \
    float bj = 0.f;                                                          \
    float emit_next = emB[(size_t)(TN_HI) * CK + sj];                        \
    __syncthreads();                                                         \
    {   const float mw = wave_max(bj + emit_next);                           \
        if (l == 0) wmaxlS[0][w] = mw; }                                     \
    __syncthreads();                                                         \
    float Mref;                                                              \
    {   const float4 wa = *reinterpret_cast<const float4*>(&wmaxlS[0][0]);   \
        const float4 wb = *reinterpret_cast<const float4*>(&wmaxlS[0][4]);   \
        Mref = fmaxf(fmaxf(fmaxf(wa.x, wa.y), fmaxf(wa.z, wa.w)),            \
                     fmaxf(fmaxf(wb.x, wb.y), fmaxf(wb.z, wb.w))) + SHIFT; } \
    __syncthreads();                                                         \
    for (int tn = (TN_HI); tn >= (TN_LO); --tn) {                            \
        const float emit_t = emit_next;                                      \
        const int nxt = (tn - 1 > (TN_LO)) ? (tn - 1) : (TN_LO);             \
        emit_next = emB[(size_t)nxt * CK + sj];                              \
        const int bsel = tn & 1;                                             \
        const float v = bj + emit_t;                                         \
        const float mw = wave_max(v);                                        \
        if (l == 0) wmaxlS[bsel][w] = mw;                                    \
        const float pv = __expf(v - Mref);                                   \
        if (l < 32) pbufS[bsel][w * 32 + l] = (_Float16)pv;                  \
        lds_barrier();                                                       \
        const float4 wa = *reinterpret_cast<const float4*>(&wmaxlS[bsel][0]);\
        const float4 wb = *reinterpret_cast<const float4*>(&wmaxlS[bsel][4]);\
        const float Mnext = fmaxf(fmaxf(fmaxf(wa.x, wa.y), fmaxf(wa.z, wa.w)), \
                                  fmaxf(fmaxf(wb.x, wb.y), fmaxf(wb.z, wb.w))) + SHIFT; \
        MFMA_STEP(pbufS[bsel])                                               \
        const float s = nsel ? accB[0] : accA[0];                            \
        const float bnew = Mref + __logf(s);                                 \
        bj = (mask_lds[tn] != 0.f) ? bnew : bj;                              \
        Mref = Mnext;                                                        \
    }                                                                        \
    if (l < 32) (OUTP)[w * 32 + l] = bj; }

// 8 segments {64 x7, 63}; boundaries b_k = 64k. 128 WGs x 1024 threads:
// WG = (pair 0..3, chain b); sub-block s = tid>>9 runs group grp = 2*pair+s.
// Sub-blocks share only read-only mask_lds; pbuf/wmaxl are sub-indexed, so
// anonymous block-wide barriers only need EQUAL TOTAL COUNTS per pair:
//   grp0: 2+64 (fwd) + 1+2+3 (probe) + 1 pad = 73 | grp1..5: 3+64+1+2+3 = 73
//   grp6: 3+64 = 67                              | grp7: 3+63 + 1 pad  = 67
// Purpose: halve WG count (256 -> 128) to test dispatch-skew theory of the
// ~24 us fixed cost. Math identical to R23.
__global__ __launch_bounds__(1024, 1) void crf_seg_kernel(
    const float* __restrict__ emissions,    // [B,T,K]
    const int* __restrict__ tags,           // [B,T]
    const int* __restrict__ mask,           // [B,T] (bool -> int32)
    const float* __restrict__ trans,        // [K,K]
    float* __restrict__ ws)
{
    const int tid = threadIdx.x;
    const int sub = tid >> 9;                // 0/1 sub-block
    const int t5 = tid & 511;
    const int w = t5 >> 6;
    const int l = tid & 63;
    const int ko8 = ((l >> 4) & 3) * 8;
    const int colg = w * 32 + (l & 15);
    const int nsel = (l >> 4) & 1;
    const int sj = w * 32 + nsel * 16 + (l & 15);
    const int pair = blockIdx.x >> 5;        // 0..3
    const int b = blockIdx.x & 31;
    const int grp = pair * 2 + sub;          // 0..7

    __shared__ __align__(16) _Float16 pbuf[2][2][CK];
    __shared__ __align__(16) float wmaxl[2][2][8];
    __shared__ float mask_lds[CT];

    _Float16 (*const pbufS)[CK] = pbuf[sub];
    float (*const wmaxlS)[8] = wmaxl[sub];

    const float* emB = emissions + (size_t)b * CT * CK;
    const int* tagB = tags + b * CT;
    const int* maskB = mask + b * CT;
    if (tid < CT) mask_lds[tid] = maskB[tid] ? 1.f : 0.f;

    // numerator partial: each sub's wave 0 covers t = 64*grp + l
    if (t5 < 64) {
        const int t = 64 * grp + l;
        const float mf = maskB[t] ? 1.f : 0.f;
        float num = emB[(size_t)t * CK + tagB[t]] * mf;
        if (t >= 1) num += trans[(size_t)tagB[t - 1] * CK + tagB[t]] * mf;
        #pragma unroll
        for (int off = 32; off > 0; off >>= 1) num += __shfl_down(num, off, 64);
        if (l == 0) ws[NUMOFF + grp * CB + b] = num;
    }

    const int lo1 = (grp == 0) ? 1 : (64 * grp + 1);
    const int hi1 = (grp == 7) ? 511 : (64 * grp + 64);
    const int slot1 = (grp == 0) ? 0 : (6 + grp);
    float* const out1 = ws + 64 + (size_t)slot1 * CB * CK + (size_t)b * CK;

    if (grp == 0) {
        FWD_RUN(1, 64, emB[sj], out1)
    } else {
        BWD_RUN(lo1, hi1, out1)
    }

    if (grp <= 5) {
        // phase 2: L=3 direction probe FA_{grp+2} ending at boundary 64*(grp+2)
        const int phi = 64 * (grp + 2);
        const int plo = phi - 2;
        float* const out2 = ws + 64 + (size_t)(grp + 1) * CB * CK + (size_t)b * CK;
        __syncthreads();   // order phase-1 LDS reads before phase-2 writes
        FWD_RUN(plo, phi, 0.f, out2)
    }

    // barrier-count padding (see header comment)
    if (grp == 0 || grp == 7) __syncthreads();
}

__device__ inline float block_lse(float v, float* red, int tid) {
    const int wid = tid >> 6, lane = tid & 63;
    float mx = v;
    #pragma unroll
    for (int off = 32; off > 0; off >>= 1) mx = fmaxf(mx, __shfl_down(mx, off, 64));
    mx = __shfl(mx, 0, 64);
    if (lane == 0) red[wid] = mx;
    __syncthreads();
    const float g = fmaxf(fmaxf(red[0], red[1]), fmaxf(red[2], red[3]));
    float ex = __expf(v - g);
    #pragma unroll
    for (int off = 32; off > 0; off >>= 1) ex += __shfl_down(ex, off, 64);
    if (lane == 0) red[4 + wid] = ex;
    __syncthreads();
    const float r = g + __logf(red[4] + red[5] + red[6] + red[7]);
    __syncthreads();
    return r;
}

// Telescoped logZ:
// logZ = LSE(FA1+FB1) + sum_{k=2..7} [LSE(FA_k+FB_k) - LSE(FA_k)]
__global__ void crf_combine_kernel(float* __restrict__ ws) {
    const int b = blockIdx.x;
    const int tid = threadIdx.x;                 // 256 threads
    __shared__ float red[8];

    if (tid == 0) {
        float num = 0.f;
        #pragma unroll
        for (int g = 0; g < 8; ++g) num += ws[NUMOFF + g * CB + b];
        ws[CB + b] = num;
    }

    const float* base = ws + 64;
    float r;
    {
        const float FA1 = base[0 * CB * CK + b * CK + tid];
        const float FB1 = base[7 * CB * CK + b * CK + tid];
        r = block_lse(FA1 + FB1, red, tid);
    }
    #pragma unroll
    for (int k = 2; k <= 7; ++k) {
        const float FAk = base[(size_t)(k - 1) * CB * CK + b * CK + tid];
        const float FBk = base[(size_t)(6 + k) * CB * CK + b * CK + tid];
        r += block_lse(FAk + FBk, red, tid);
        r -= block_lse(FAk, red, tid);
    }
    if (tid == 0) ws[b] = r;
}

__global__ void crf_finalize_kernel(const float* __restrict__ ws,
                                    float* __restrict__ out) {
    float v = 0.f;
    if ((int)threadIdx.x < CB) v = ws[threadIdx.x] - ws[CB + threadIdx.x];
    #pragma unroll
    for (int off = 32; off > 0; off >>= 1) v += __shfl_down(v, off, 64);
    if (threadIdx.x == 0) out[0] = v * (1.f / CB);
}

extern "C" void kernel_launch(void* const* d_in, const int* in_sizes, int n_in,
                              void* d_out, int out_size, void* d_ws, size_t ws_size,
                              hipStream_t stream) {
    const float* emissions = (const float*)d_in[0];
    const int* tags = (const int*)d_in[1];
    const int* mask = (const int*)d_in[2];
    const float* trans = (const float*)d_in[3];
    float* out = (float*)d_out;
    float* ws = (float*)d_ws;

    crf_seg_kernel<<<4 * CB, 1024, 0, stream>>>(emissions, tags, mask, trans, ws);
    crf_combine_kernel<<<CB, 256, 0, stream>>>(ws);
    crf_finalize_kernel<<<1, 64, 0, stream>>>(ws, out);
}

// Round 25
// 68.273 us; speedup vs baseline: 1.8847x; 1.8847x over previous
//
#include <hip/hip_runtime.h>
#include <stdint.h>

#define CB 32
#define CT 512
#define CK 256
#define SHIFT 5.0f
#define NUMOFF (64 + 14 * CB * CK)   // numerator partials: [8][CB]

typedef _Float16 f16x8 __attribute__((ext_vector_type(8)));
typedef float f32x4 __attribute__((ext_vector_type(4)));

__device__ inline uint32_t pk2(float a, float b) {
    return __builtin_bit_cast(uint32_t,
        __builtin_amdgcn_cvt_pkrtz(__expf(a), __expf(b)));
}

// Barrier draining LDS only; global prefetches stay in flight.
__device__ inline void lds_barrier() {
    asm volatile("s_waitcnt lgkmcnt(0)\n\ts_barrier" ::: "memory");
}

template <int CTRL>
__device__ inline float dpp_maxf(float x) {
    int yi = __builtin_amdgcn_update_dpp(
        __builtin_bit_cast(int, x), __builtin_bit_cast(int, x),
        CTRL, 0xF, 0xF, false);
    return fmaxf(x, __builtin_bit_cast(float, yi));
}

__device__ inline float wave_max(float x) {
    x = dpp_maxf<0x111>(x);
    x = dpp_maxf<0x112>(x);
    x = dpp_maxf<0x114>(x);
    x = dpp_maxf<0x118>(x);
    x = dpp_maxf<0x142>(x);
    x = dpp_maxf<0x143>(x);
    return __builtin_bit_cast(float,
        __builtin_amdgcn_readlane(__builtin_bit_cast(int, x), 63));
}

// FWD B-frag: B[k][col] = exp(trans[k][col]) (strided rows).
#define MKB_F(kt, n) f16x8 B_##kt##_##n; {                                   \
    const float* tp = trans + (size_t)((kt) * 32 + ko8) * CK + (colg + (n) * 16); \
    uint4 u_;                                                                \
    u_.x = pk2(tp[0],      tp[CK]);                                          \
    u_.y = pk2(tp[2 * CK], tp[3 * CK]);                                      \
    u_.z = pk2(tp[4 * CK], tp[5 * CK]);                                      \
    u_.w = pk2(tp[6 * CK], tp[7 * CK]);                                      \
    B_##kt##_##n = __builtin_bit_cast(f16x8, u_); }

// BWD B-frag: B[k][col] = exp(trans[col][k]) (contiguous k).
#define MKB_B(kt, n) f16x8 B_##kt##_##n; {                                   \
    const float* tp = trans + (size_t)(colg + (n) * 16) * CK + ((kt) * 32 + ko8); \
    uint4 u_;                                                                \
    u_.x = pk2(tp[0], tp[1]);                                                \
    u_.y = pk2(tp[2], tp[3]);                                                \
    u_.z = pk2(tp[4], tp[5]);                                                \
    u_.w = pk2(tp[6], tp[7]);                                                \
    B_##kt##_##n = __builtin_bit_cast(f16x8, u_); }

#define LOADB(MK) MK(0,0) MK(0,1) MK(1,0) MK(1,1) MK(2,0) MK(2,1) MK(3,0) MK(3,1) \
                  MK(4,0) MK(4,1) MK(5,0) MK(5,1) MK(6,0) MK(6,1) MK(7,0) MK(7,1)

#define MM(kt)                                                               \
    accA = __builtin_amdgcn_mfma_f32_16x16x32_f16(a##kt##_, B_##kt##_0, accA, 0, 0, 0); \
    accB = __builtin_amdgcn_mfma_f32_16x16x32_f16(a##kt##_, B_##kt##_1, accB, 0, 0, 0);

#define MFMA_STEP(pb)                                                        \
    f16x8 a0_ = *reinterpret_cast<const f16x8*>((pb) + 0   + ko8);           \
    f16x8 a1_ = *reinterpret_cast<const f16x8*>((pb) + 32  + ko8);           \
    f16x8 a2_ = *reinterpret_cast<const f16x8*>((pb) + 64  + ko8);           \
    f16x8 a3_ = *reinterpret_cast<const f16x8*>((pb) + 96  + ko8);           \
    f16x8 a4_ = *reinterpret_cast<const f16x8*>((pb) + 128 + ko8);           \
    f16x8 a5_ = *reinterpret_cast<const f16x8*>((pb) + 160 + ko8);           \
    f16x8 a6_ = *reinterpret_cast<const f16x8*>((pb) + 192 + ko8);           \
    f16x8 a7_ = *reinterpret_cast<const f16x8*>((pb) + 224 + ko8);           \
    f32x4 accA = {0.f, 0.f, 0.f, 0.f};                                       \
    f32x4 accB = {0.f, 0.f, 0.f, 0.f};                                       \
    MM(0) MM(1) MM(2) MM(3) MM(4) MM(5) MM(6) MM(7)

// Full fwd run over t in [T_LO, T_HI], alpha init AJ_INIT, result -> OUTP.
#define FWD_RUN(T_LO, T_HI, AJ_INIT, OUTP) {                                 \
    LOADB(MKB_F)                                                             \
    float aj = (AJ_INIT);                                                    \
    float emit_next = emB[(size_t)(T_LO) * CK + sj];                         \
    {   const float mw = wave_max(aj);                                       \
        if (l == 0) wmaxl[0][w] = mw; }                                      \
    __syncthreads();                                                         \
    float Mref;                                                              \
    {   const float4 wa = *reinterpret_cast<const float4*>(&wmaxl[0][0]);    \
        const float4 wb = *reinterpret_cast<const float4*>(&wmaxl[0][4]);    \
        Mref = fmaxf(fmaxf(fmaxf(wa.x, wa.y), fmaxf(wa.z, wa.w)),            \
                     fmaxf(fmaxf(wb.x, wb.y), fmaxf(wb.z, wb.w))) + SHIFT; } \
    __syncthreads();                                                         \
    for (int t = (T_LO); t <= (T_HI); ++t) {                                 \
        const float emit_t = emit_next;                                      \
        const int nxt = (t + 1 <= (T_HI)) ? (t + 1) : (T_HI);                \
        emit_next = emB[(size_t)nxt * CK + sj];                              \
        const int bsel = t & 1;                                              \
        const float mw = wave_max(aj);                                       \
        if (l == 0) wmaxl[bsel][w] = mw;                                     \
        const float pv = __expf(aj - Mref);                                  \
        if (l < 32) pbuf[bsel][w * 32 + l] = (_Float16)pv;                   \
        lds_barrier();                                                       \
        const float4 wa = *reinterpret_cast<const float4*>(&wmaxl[bsel][0]); \
        const float4 wb = *reinterpret_cast<const float4*>(&wmaxl[bsel][4]); \
        const float Mnext = fmaxf(fmaxf(fmaxf(wa.x, wa.y), fmaxf(wa.z, wa.w)), \
                                  fmaxf(fmaxf(wb.x, wb.y), fmaxf(wb.z, wb.w))) + SHIFT; \
        MFMA_STEP(pbuf[bsel])                                                \
        const float s = nsel ? accB[0] : accA[0];                            \
        const float anew = Mref + __logf(s) + emit_t;                        \
        aj = (mask_lds[t] != 0.f) ? anew : aj;                               \
        Mref = Mnext;                                                        \
    }                                                                        \
    if (l < 32) (OUTP)[w * 32 + l] = aj; }

// Full bwd run over tn in [TN_HI down to TN_LO], 0-init, result -> OUTP.
#define BWD_RUN(TN_LO, TN_HI, OUTP) {                                        \
    LOADB(MKB_B)                                                             \
    float bj = 0.f;                                                          \
    float emit_next = emB[(size_t)(TN_HI) * CK + sj];                        \
    __syncthreads();                                                         \
    {   const float mw = wave_max(bj + emit_next);                           \
        if (l == 0) wmaxl[0][w] = mw; }                                      \
    __syncthreads();                                                         \
    float Mref;                                                              \
    {   const float4 wa = *reinterpret_cast<const float4*>(&wmaxl[0][0]);    \
        const float4 wb = *reinterpret_cast<const float4*>(&wmaxl[0][4]);    \
        Mref = fmaxf(fmaxf(fmaxf(wa.x, wa.y), fmaxf(wa.z, wa.w)),            \
                     fmaxf(fmaxf(wb.x, wb.y), fmaxf(wb.z, wb.w))) + SHIFT; } \
    __syncthreads();                                                         \
    for (int tn = (TN_HI); tn >= (TN_LO); --tn) {                            \
        const float emit_t = emit_next;                                      \
        const int nxt = (tn - 1 > (TN_LO)) ? (tn - 1) : (TN_LO);             \
        emit_next = emB[(size_t)nxt * CK + sj];                              \
        const int bsel = tn & 1;                                             \
        const float v = bj + emit_t;                                         \
        const float mw = wave_max(v);                                        \
        if (l == 0) wmaxl[bsel][w] = mw;                                     \
        const float pv = __expf(v - Mref);                                   \
        if (l < 32) pbuf[bsel][w * 32 + l] = (_Float16)pv;                   \
        lds_barrier();                                                       \
        const float4 wa = *reinterpret_cast<const float4*>(&wmaxl[bsel][0]); \
        const float4 wb = *reinterpret_cast<const float4*>(&wmaxl[bsel][4]); \
        const float Mnext = fmaxf(fmaxf(fmaxf(wa.x, wa.y), fmaxf(wa.z, wa.w)), \
                                  fmaxf(fmaxf(wb.x, wb.y), fmaxf(wb.z, wb.w))) + SHIFT; \
        MFMA_STEP(pbuf[bsel])                                                \
        const float s = nsel ? accB[0] : accA[0];                            \
        const float bnew = Mref + __logf(s);                                 \
        bj = (mask_lds[tn] != 0.f) ? bnew : bj;                              \
        Mref = Mnext;                                                        \
    }                                                                        \
    if (l < 32) (OUTP)[w * 32 + l] = bj; }

// 8 segments {64 x7, 63}; boundaries b_k = 64k (k=1..7).
// 8 groups x 32 chains = 256 blocks, 1/CU. FA_1 exact (grp0 phase1);
// FB_k = full bwd over segment k+1 (grp k phase1, k=1..7). FA_k (k=2..7) =
// L=3-step DIRECTION probes (scale cancels in the telescope) as phase2 on
// grps 0..5. Max steps/group = 67. Numerator partials: wave 0 of each block
// covers t in [64*grp, 64*grp+63] -> ws[NUMOFF + grp*CB + b].
// ws: [0..31] logZ | [32..63] numerator | 64 + slot*8192 + b*256 + j
//   slots: FA_k -> k-1 (0..6), FB_k -> 6+k (7..13) | NUMOFF: [8][CB] partials
__global__ __launch_bounds__(512, 1) void crf_seg_kernel(
    const float* __restrict__ emissions,    // [B,T,K]
    const int* __restrict__ tags,           // [B,T]
    const int* __restrict__ mask,           // [B,T] (bool -> int32)
    const float* __restrict__ trans,        // [K,K]
    float* __restrict__ ws)
{
    const int tid = threadIdx.x;
    const int w = tid >> 6;
    const int l = tid & 63;
    const int ko8 = ((l >> 4) & 3) * 8;
    const int colg = w * 32 + (l & 15);
    const int nsel = (l >> 4) & 1;
    const int sj = w * 32 + nsel * 16 + (l & 15);
    const int grp = blockIdx.x >> 5;         // 0..7, block-uniform
    const int b = blockIdx.x & 31;

    __shared__ __align__(16) _Float16 pbuf[2][CK];
    __shared__ __align__(16) float wmaxl[2][8];
    __shared__ float mask_lds[CT];

    const float* emB = emissions + (size_t)b * CT * CK;
    const int* tagB = tags + b * CT;
    const int* maskB = mask + b * CT;
    mask_lds[tid] = maskB[tid] ? 1.f : 0.f;

    // numerator partial: wave 0, t = 64*grp + l
    if (tid < 64) {
        const int t = 64 * grp + l;
        const float mf = maskB[t] ? 1.f : 0.f;
        float num = emB[(size_t)t * CK + tagB[t]] * mf;
        if (t >= 1) num += trans[(size_t)tagB[t - 1] * CK + tagB[t]] * mf;
        #pragma unroll
        for (int off = 32; off > 0; off >>= 1) num += __shfl_down(num, off, 64);
        if (l == 0) ws[NUMOFF + grp * CB + b] = num;
    }

    // phase-1 ranges: grp0 fwd [1,64]; grp1..6 bwd [64g+1, 64g+64];
    // grp7 bwd [449,511]
    const int lo1 = (grp == 0) ? 1 : (64 * grp + 1);
    const int hi1 = (grp == 7) ? 511 : (64 * grp + 64);
    const int slot1 = (grp == 0) ? 0 : (6 + grp);
    float* const out1 = ws + 64 + (size_t)slot1 * CB * CK + (size_t)b * CK;

    if (grp == 0) {
        FWD_RUN(1, 64, emB[sj], out1)
    } else {
        BWD_RUN(lo1, hi1, out1)
    }

    if (grp <= 5) {
        // phase 2: direction probe FA_{grp+2} over last 3 steps before
        // boundary b_{grp+2} = 64*(grp+2).
        const int phi = 64 * (grp + 2);
        const int plo = phi - 2;
        float* const out2 = ws + 64 + (size_t)(grp + 1) * CB * CK + (size_t)b * CK;
        __syncthreads();   // order phase-1 LDS reads before phase-2 writes
        FWD_RUN(plo, phi, 0.f, out2)
    }
}

__device__ inline float block_lse(float v, float* red, int tid) {
    const int wid = tid >> 6, lane = tid & 63;
    float mx = v;
    #pragma unroll
    for (int off = 32; off > 0; off >>= 1) mx = fmaxf(mx, __shfl_down(mx, off, 64));
    mx = __shfl(mx, 0, 64);
    if (lane == 0) red[wid] = mx;
    __syncthreads();
    const float g = fmaxf(fmaxf(red[0], red[1]), fmaxf(red[2], red[3]));
    float ex = __expf(v - g);
    #pragma unroll
    for (int off = 32; off > 0; off >>= 1) ex += __shfl_down(ex, off, 64);
    if (lane == 0) red[4 + wid] = ex;
    __syncthreads();
    const float r = g + __logf(red[4] + red[5] + red[6] + red[7]);
    __syncthreads();
    return r;
}

// Telescoped logZ:
// logZ = LSE(FA1+FB1) + sum_{k=2..7} [LSE(FA_k+FB_k) - LSE(FA_k)]
// Numerator: sum of 8 precomputed partials.
__global__ void crf_combine_kernel(float* __restrict__ ws) {
    const int b = blockIdx.x;
    const int tid = threadIdx.x;                 // 256 threads
    __shared__ float red[8];

    if (tid == 0) {
        float num = 0.f;
        #pragma unroll
        for (int g = 0; g < 8; ++g) num += ws[NUMOFF + g * CB + b];
        ws[CB + b] = num;
    }

    const float* base = ws + 64;
    float r;
    {
        const float FA1 = base[0 * CB * CK + b * CK + tid];
        const float FB1 = base[7 * CB * CK + b * CK + tid];
        r = block_lse(FA1 + FB1, red, tid);
    }
    #pragma unroll
    for (int k = 2; k <= 7; ++k) {
        const float FAk = base[(size_t)(k - 1) * CB * CK + b * CK + tid];
        const float FBk = base[(size_t)(6 + k) * CB * CK + b * CK + tid];
        r += block_lse(FAk + FBk, red, tid);
        r -= block_lse(FAk, red, tid);
    }
    if (tid == 0) ws[b] = r;
}

__global__ void crf_finalize_kernel(const float* __restrict__ ws,
                                    float* __restrict__ out) {
    float v = 0.f;
    if ((int)threadIdx.x < CB) v = ws[threadIdx.x] - ws[CB + threadIdx.x];
    #pragma unroll
    for (int off = 32; off > 0; off >>= 1) v += __shfl_down(v, off, 64);
    if (threadIdx.x == 0) out[0] = v * (1.f / CB);
}

extern "C" void kernel_launch(void* const* d_in, const int* in_sizes, int n_in,
                              void* d_out, int out_size, void* d_ws, size_t ws_size,
                              hipStream_t stream) {
    const float* emissions = (const float*)d_in[0];
    const int* tags = (const int*)d_in[1];
    const int* mask = (const int*)d_in[2];
    const float* trans = (const float*)d_in[3];
    float* out = (float*)d_out;
    float* ws = (float*)d_ws;

    crf_seg_kernel<<<8 * CB, 512, 0, stream>>>(emissions, tags, mask, trans, ws);
    crf_combine_kernel<<<CB, 256, 0, stream>>>(ws);
    crf_finalize_kernel<<<1, 64, 0, stream>>>(ws, out);
}